// Round 6
// baseline (314.213 us; speedup 1.0000x reference)
//
#include <hip/hip_runtime.h>
#include <hip/hip_bf16.h>
#include <math.h>

// ============================================================================
// MultiHeadAttention: B=2, S=2048, H=1024, NH=16, HD=64
// I/O: fp32 (x, Wq/bq, Wk/bk, Wv/bv), int32 mask; out fp32.
// Internal: bf16 MFMA (16x16x32) with fp32 accum.
// Pipeline: xcast -> wtrans -> maskpack -> qkv_gemm(V fused transpose) -> attn
//
// Round-6: bisect round-5's failure. KEEP the barrier-free direct global->VGPR
// K/V structure (mapping verified identical to round-4's LDS path). REVERT the
// two unproven micro-ops that were bundled with it:
//   - v_cvt_pk_bf16_f32 inline asm  -> f2bf scalar RNE cast (m240: compiler
//     path is correct & fast; cvt_pk semantics on gfx950 unverified here)
//   - post-cvt AND-mask LUT         -> round-4 bit-test (s -> -14000) pre-exp2
// attn now has ZERO __syncthreads (waves fully independent; Ps is per-wave).
//
// MEMORY PLAN:
//   d_ws (25MB used):
//     [0,8M)   Qw  bf16 [b][nh][s][hd]  (pre-scaled by 0.125*log2e)
//     [8M,16M) Kw  bf16 [b][nh][s][hd]
//     [16M,24M)Vtw bf16 [b][nh][hd][s]  (transposed, written by qkv_gemm)
//     [24M,25M)mb  u64 bitmask [b][s][S/64]
//   (attn's K-prefetch at t=NT-1 reads 256KB past Kh(bnh=31) into Vtw: valid
//    ws memory, values never used.)
//   d_out (16MB fp32) doubles as scratch BEFORE attn (dead until epilogue):
//     [0,8M)   Xb  bf16 [b*s][h]
//     [8M,14M) WT  bf16 3x [n][k] (transposed weights)
// ============================================================================

#define DI __device__ __forceinline__

typedef unsigned short u16;
typedef unsigned int u32;
typedef unsigned long long u64;
typedef __attribute__((ext_vector_type(8))) short bf16x8;
typedef __attribute__((ext_vector_type(4))) float f32x4;

constexpr int BB = 2, SS = 2048, HH = 1024, NHEAD = 16, HDIM = 64;

DI u16 f2bf(float f) {
  __hip_bfloat16 h = __float2bfloat16(f);
  union { __hip_bfloat16 h; u16 u; } c; c.h = h; return c.u;
}

// async global->LDS, 16B per lane; LDS dest = wave-uniform base + lane*16
DI void gload_lds16(const void* g, const void* l) {
  __builtin_amdgcn_global_load_lds(
      (const __attribute__((address_space(1))) u32*)(u64)g,
      (__attribute__((address_space(3))) u32*)(u32)(u64)l,
      16, 0, 0);
}

// ---------------------------------------------------------------------------
// x fp32 -> bf16
__global__ void xcast(const float* __restrict__ x, u16* __restrict__ xb) {
  const size_t i = ((size_t)blockIdx.x * 256 + threadIdx.x) * 8;
  float4 f0 = *(const float4*)(x + i);
  float4 f1 = *(const float4*)(x + i + 4);
  bf16x8 v;
  v[0] = (short)f2bf(f0.x); v[1] = (short)f2bf(f0.y);
  v[2] = (short)f2bf(f0.z); v[3] = (short)f2bf(f0.w);
  v[4] = (short)f2bf(f1.x); v[5] = (short)f2bf(f1.y);
  v[6] = (short)f2bf(f1.z); v[7] = (short)f2bf(f1.w);
  *(bf16x8*)(xb + i) = v;
}

// ---------------------------------------------------------------------------
// W fp32 [k][n] -> WT bf16 [n][k], 3 matrices
__global__ void wtrans(const float* __restrict__ Wq, const float* __restrict__ Wk,
                       const float* __restrict__ Wv, u16* __restrict__ WT) {
  __shared__ u16 tile[64][65];
  const float* W = (blockIdx.z == 0) ? Wq : (blockIdx.z == 1) ? Wk : Wv;
  u16* Wt = WT + (size_t)blockIdx.z * HH * HH;
  const int n0 = blockIdx.x * 64, k0 = blockIdx.y * 64;
  for (int i = threadIdx.x; i < 64 * 64; i += 256) {
    int r = i >> 6, c = i & 63;
    tile[r][c] = f2bf(W[(size_t)(k0 + r) * HH + n0 + c]);
  }
  __syncthreads();
  for (int i = threadIdx.x; i < 64 * 64; i += 256) {
    int r = i >> 6, c = i & 63;
    Wt[(size_t)(n0 + r) * HH + k0 + c] = tile[c][r];
  }
}

// ---------------------------------------------------------------------------
// mask int32 {0,1} -> packed bits (bit j of word g = mask[g*64+j])
__global__ void maskpack(const int* __restrict__ mask, u64* __restrict__ mb) {
  const size_t idx = (size_t)blockIdx.x * 256 + threadIdx.x;
  const int v = mask[idx];
  const u64 bal = __ballot(v != 0);
  if ((threadIdx.x & 63) == 0) mb[idx >> 6] = bal;
}

// ---------------------------------------------------------------------------
// C[m][n] = X[m][k] * W[k][n] (+bias) for z in {Q,K,V}; X bf16 [4096][1024],
// WT bf16 [n][k]. Tile 128x128xBK64, 4 waves each 64x64 (4x4 frags 16x16x32).
// LDS rows are 128B; XOR-swizzle byte^=((row&7)<<4) via pre-swizzled global
// source (G21). z==2 (V) writes output TRANSPOSED [bnh][hd][s].
__global__ __launch_bounds__(256) void qkv_gemm(
    const u16* __restrict__ X, const u16* __restrict__ WTall,
    const float* __restrict__ bq, const float* __restrict__ bk,
    const float* __restrict__ bv,
    u16* __restrict__ Qo, u16* __restrict__ Ko, u16* __restrict__ Vo) {
  __shared__ alignas(128) u16 As[128 * 64];
  __shared__ alignas(128) u16 Bs[128 * 64];

  const int z = blockIdx.z;
  const u16* Wt = WTall + (size_t)z * HH * HH;
  const float* bias = (z == 0) ? bq : (z == 1) ? bk : bv;
  u16* Out = (z == 0) ? Qo : (z == 1) ? Ko : Vo;
  // fold 1/sqrt(HD) AND log2(e) into Q (attn works in exp2 domain)
  const float oscale = (z == 0) ? 0.18033688011112042f : 1.0f;

  const int tid = threadIdx.x;
  const int lane = tid & 63;
  const int w = tid >> 6;
  const int wm = (w >> 1) * 64, wn = (w & 1) * 64;
  const int lr = lane & 15, lkg = lane >> 4;
  const int m0 = blockIdx.y * 128, n0 = blockIdx.x * 128;

  u32 srow[4], scol[4];
#pragma unroll
  for (int i = 0; i < 4; ++i) {
    u32 f = i * 4096 + w * 1024 + lane * 16;
    u32 g = f ^ (((f >> 7) & 7) << 4);
    srow[i] = g >> 7;
    scol[i] = (g & 127) >> 1;
  }

  u32 aoff[4][2], boff[4][2];
#pragma unroll
  for (int mf = 0; mf < 4; ++mf)
#pragma unroll
    for (int ks = 0; ks < 2; ++ks) {
      int row = wm + mf * 16 + lr;
      aoff[mf][ks] = (u32)((row * 128 + ks * 64 + lkg * 16) ^ ((row & 7) << 4));
      row = wn + mf * 16 + lr;
      boff[mf][ks] = (u32)((row * 128 + ks * 64 + lkg * 16) ^ ((row & 7) << 4));
    }

  f32x4 acc[4][4];
#pragma unroll
  for (int i = 0; i < 4; ++i)
#pragma unroll
    for (int j = 0; j < 4; ++j) acc[i][j] = {0.f, 0.f, 0.f, 0.f};

  const u16* Xb = X + (size_t)m0 * HH;
  const u16* Wb = Wt + (size_t)n0 * HH;

  auto stage = [&](int kt) {
    const int k0 = kt * 64;
#pragma unroll
    for (int i = 0; i < 4; ++i) {
      gload_lds16(Xb + (size_t)srow[i] * HH + k0 + scol[i],
                  (const char*)As + i * 4096 + w * 1024);
      gload_lds16(Wb + (size_t)srow[i] * HH + k0 + scol[i],
                  (const char*)Bs + i * 4096 + w * 1024);
    }
  };

  stage(0);
  const int NT = HH / 64;  // 16
  for (int kt = 0; kt < NT; ++kt) {
    __syncthreads();
    bf16x8 a[2][4], bfr[2][4];
#pragma unroll
    for (int ks = 0; ks < 2; ++ks)
#pragma unroll
      for (int i = 0; i < 4; ++i) {
        a[ks][i] = *(const bf16x8*)((const char*)As + aoff[i][ks]);
        bfr[ks][i] = *(const bf16x8*)((const char*)Bs + boff[i][ks]);
      }
    __syncthreads();
    if (kt + 1 < NT) stage(kt + 1);
    __builtin_amdgcn_s_setprio(1);
#pragma unroll
    for (int ks = 0; ks < 2; ++ks)
#pragma unroll
      for (int mf = 0; mf < 4; ++mf)
#pragma unroll
        for (int nf = 0; nf < 4; ++nf)
          acc[mf][nf] = __builtin_amdgcn_mfma_f32_16x16x32_bf16(
              a[ks][mf], bfr[ks][nf], acc[mf][nf], 0, 0, 0);
    __builtin_amdgcn_s_setprio(0);
  }

  // epilogue: C/D layout col=lane&15, row=(lane>>4)*4+reg
#pragma unroll
  for (int mf = 0; mf < 4; ++mf)
#pragma unroll
    for (int nf = 0; nf < 4; ++nf) {
      const int gn = n0 + wn + nf * 16 + lr;
      const float bvv = bias[gn];
      const int nh = gn >> 6, hd = gn & 63;
#pragma unroll
      for (int r = 0; r < 4; ++r) {
        const int gm = m0 + wm + mf * 16 + lkg * 4 + r;
        const int bb = gm >> 11, ss = gm & 2047;
        const float v = (acc[mf][nf][r] + bvv) * oscale;
        if (z < 2)
          Out[(((size_t)bb * NHEAD + nh) * SS + ss) * HDIM + hd] = f2bf(v);
        else  // V: fused transpose -> [bnh][hd][s]
          Out[(((size_t)bb * NHEAD + nh) * HDIM + hd) * SS + ss] = f2bf(v);
      }
    }
}

// ---------------------------------------------------------------------------
// Flash attention, barrier-free. Block = 4 independent waves, 64 q-rows
// (16 per wave); KV tiles of 64. Q (prescaled, exp2 domain) in regs.
// K/V fragments loaded DIRECTLY global->VGPR (L2-resident; 64B-coalesced
// per 4-lane group). QK^T = mfma(K,Q) -> S[kv][q]: lane owns q-col=lane&15,
// kv = kvb*16 + lkg*4 + r. Mask: bit-test -> s=-14000 -> exp2 underflow -> 0
// (round-4-verified). P cast via f2bf (RNE). l via MFMA with ones B-frag.
__global__ __launch_bounds__(256, 4) void attn(
    const u16* __restrict__ Q, const u16* __restrict__ K,
    const u16* __restrict__ Vt, const u64* __restrict__ mb,
    float* __restrict__ out) {
  __shared__ alignas(16) u16 Ps[4][16][72];  // per-wave, stride 144B

  const int tid = threadIdx.x, lane = tid & 63, w = tid >> 6;

  const int nh = blockIdx.x, qt = blockIdx.y, b = blockIdx.z;
  const int bnh = b * NHEAD + nh;
  const u16* Qh = Q + (size_t)bnh * SS * HDIM;
  const u16* Kh = K + (size_t)bnh * SS * HDIM;
  const u16* Vh = Vt + (size_t)bnh * HDIM * SS;
  const int q0 = qt * 64;

  const int lr = lane & 15, lkg = lane >> 4;
  const int qrow_lane = q0 + w * 16 + lr;  // this lane's q row (score col)

  // Q fragments (B operand): rows w*16 + lr, k = h*32 + lkg*8 + j
  bf16x8 qf[2];
#pragma unroll
  for (int h = 0; h < 2; ++h)
    qf[h] = *(const bf16x8*)(Qh + (size_t)qrow_lane * HDIM + h * 32 + lkg * 8);

  // all-ones B fragment for l = P * 1
  bf16x8 ones;
#pragma unroll
  for (int j = 0; j < 8; ++j) ones[j] = (short)0x3F80;

  f32x4 oacc[4];
  f32x4 lacc = {0.f, 0.f, 0.f, 0.f};
#pragma unroll
  for (int n = 0; n < 4; ++n) oacc[n] = {0.f, 0.f, 0.f, 0.f};

  // K/V fragment registers (single-buffered; reloaded after last use)
  bf16x8 kf[4][2], vf[4][2];
  const u16* Kfl = Kh + (size_t)lr * HDIM + lkg * 8;  // + kvb*16*HDIM + h*32
  const u16* Vfl = Vh + (size_t)lr * SS + lkg * 8;    // + n*16*SS + h*32

  auto loadK = [&](int t) {
    const u16* base = Kfl + (size_t)t * 64 * HDIM;
#pragma unroll
    for (int i = 0; i < 4; ++i)
#pragma unroll
      for (int h = 0; h < 2; ++h)
        kf[i][h] = *(const bf16x8*)(base + (size_t)i * 16 * HDIM + h * 32);
  };
  auto loadV = [&](int t) {
    const u16* base = Vfl + t * 64;
#pragma unroll
    for (int n = 0; n < 4; ++n)
#pragma unroll
      for (int h = 0; h < 2; ++h)
        vf[n][h] = *(const bf16x8*)(base + (size_t)n * 16 * SS + h * 32);
  };

  const u64* mrow = mb + ((size_t)b * SS + qrow_lane) * (SS / 64);

  loadK(0);
  const int NT = SS / 64;  // 32
  for (int t = 0; t < NT; ++t) {
    loadV(t);  // used after softmax (~250cyc cover)
    const u64 sh = mrow[t] >> (lkg * 4);
    const u32 w01 = (u32)sh, w23 = (u32)(sh >> 32);

    // swapped QK^T: sacc[kvb] = S[kv][q], kv rows, q cols
    f32x4 sacc[4];
#pragma unroll
    for (int kvb = 0; kvb < 4; ++kvb) sacc[kvb] = {0.f, 0.f, 0.f, 0.f};
    __builtin_amdgcn_s_setprio(1);
#pragma unroll
    for (int kvb = 0; kvb < 4; ++kvb)
#pragma unroll
      for (int h = 0; h < 2; ++h)
        sacc[kvb] = __builtin_amdgcn_mfma_f32_16x16x32_bf16(
            kf[kvb][h], qf[h], sacc[kvb], 0, 0, 0);
    __builtin_amdgcn_s_setprio(0);

    loadK(t + 1);  // prefetch next tile's K (t=NT-1: valid ws, unused)

    // no-max softmax (round-4-verified): masked -> s=-14000 -> exp2 -> 0
#pragma unroll
    for (int kvb = 0; kvb < 4; ++kvb) {
      const u32 word = (kvb < 2) ? w01 : w23;
      const int sb = (kvb & 1) * 16;
      union { u16 h[4]; u64 d; } pk;
#pragma unroll
      for (int r = 0; r < 4; ++r) {
        float s = sacc[kvb][r];
        s = ((word >> (sb + r)) & 1u) ? -14000.0f : s;
        pk.h[r] = f2bf(__builtin_amdgcn_exp2f(s));
      }
      *(u64*)&Ps[w][lr][kvb * 16 + lkg * 4] = pk.d;
    }

    // PV: O[q][hd] += P[q][kv] * V[kv][hd]; l += P * 1
    __builtin_amdgcn_s_setprio(1);
#pragma unroll
    for (int ks = 0; ks < 2; ++ks) {
      const bf16x8 pf = *(const bf16x8*)&Ps[w][lr][ks * 32 + lkg * 8];
#pragma unroll
      for (int n = 0; n < 4; ++n)
        oacc[n] = __builtin_amdgcn_mfma_f32_16x16x32_bf16(
            pf, vf[n][ks], oacc[n], 0, 0, 0);
      lacc = __builtin_amdgcn_mfma_f32_16x16x32_bf16(pf, ones, lacc, 0, 0, 0);
    }
    __builtin_amdgcn_s_setprio(0);
  }

  // epilogue: out[b][q][nh*64+hd] fp32; l already in oacc row domain
#pragma unroll
  for (int r = 0; r < 4; ++r) {
    const float rcp = 1.0f / lacc[r];
    const int qrow = q0 + w * 16 + lkg * 4 + r;
#pragma unroll
    for (int n = 0; n < 4; ++n)
      out[((size_t)b * SS + qrow) * HH + nh * HDIM + n * 16 + lr] =
          oacc[n][r] * rcp;
  }
}

// ---------------------------------------------------------------------------
extern "C" void kernel_launch(void* const* d_in, const int* in_sizes, int n_in,
                              void* d_out, int out_size, void* d_ws,
                              size_t ws_size, hipStream_t stream) {
  const float* x = (const float*)d_in[0];
  const int* mask = (const int*)d_in[1];
  const float* Wq = (const float*)d_in[2];
  const float* bq = (const float*)d_in[3];
  const float* Wk = (const float*)d_in[4];
  const float* bk = (const float*)d_in[5];
  const float* Wv = (const float*)d_in[6];
  const float* bv = (const float*)d_in[7];
  float* out = (float*)d_out;

  char* ws = (char*)d_ws;
  const size_t MB = 1024 * 1024;
  // ws: 25MB used
  u16* Qw = (u16*)(ws + 0 * MB);
  u16* Kw = (u16*)(ws + 8 * MB);
  u16* Vtw = (u16*)(ws + 16 * MB);
  u64* mbp = (u64*)(ws + 24 * MB);
  // d_out doubles as pre-attn scratch (fully dead until attn's epilogue)
  u16* Xb = (u16*)d_out;
  u16* WT = (u16*)((char*)d_out + 8 * MB);

  xcast<<<dim3((BB * SS * HH) / (256 * 8)), 256, 0, stream>>>(x, Xb);
  wtrans<<<dim3(16, 16, 3), 256, 0, stream>>>(Wq, Wk, Wv, WT);
  maskpack<<<dim3((BB * SS * SS) / 256), 256, 0, stream>>>(mask, mbp);
  qkv_gemm<<<dim3(8, 32, 3), 256, 0, stream>>>(Xb, WT, bq, bk, bv, Qw, Kw, Vtw);
  attn<<<dim3(NHEAD, SS / 64, BB), 256, 0, stream>>>(Qw, Kw, Vtw, mbp, out);
}

// Round 7
// 150.214 us; speedup vs baseline: 2.0918x; 2.0918x over previous
//
#include <hip/hip_runtime.h>
#include <hip/hip_bf16.h>
#include <math.h>

// ============================================================================
// MultiHeadAttention: B=2, S=2048, H=1024, NH=16, HD=64
// I/O: fp32 (x, Wq/bq, Wk/bk, Wv/bv), int32 mask; out fp32.
// Internal: bf16 MFMA (16x16x32) with fp32 accum.
// Pipeline: xcast -> wtrans -> maskpack -> qkv_gemm(V fused transpose) -> attn
//
// Round-7: revert round-6's direct-to-VGPR attn (3.5x regression: 4 waves
// redundantly loading the same K/V tile oversubscribed the L1/TA pipe;
// LDS staging is DEDUPLICATION). Back to round-4's verified LDS structure,
// plus the fix round-4's post-mortem called for:
//   DOUBLE-BUFFERED K/V tiles + ONE barrier per iteration.
//   stage(t+1 -> buf^1) issues right after the top barrier; its vmcnt drain
//   happens at the NEXT top barrier, a full iteration of compute later.
//   (Round-4 staged at iteration end and drained immediately -> full
//   global->LDS latency exposed every tile.)
//
// MEMORY PLAN:
//   d_ws (25MB used):
//     [0,8M)   Qw  bf16 [b][nh][s][hd]  (pre-scaled by 0.125*log2e)
//     [8M,16M) Kw  bf16 [b][nh][s][hd]
//     [16M,24M)Vtw bf16 [b][nh][hd][s]  (transposed, written by qkv_gemm)
//     [24M,25M)mb  u64 bitmask [b][s][S/64]
//   d_out (16MB fp32) doubles as scratch BEFORE attn (dead until epilogue):
//     [0,8M)   Xb  bf16 [b*s][h]
//     [8M,14M) WT  bf16 3x [n][k] (transposed weights)
// ============================================================================

#define DI __device__ __forceinline__

typedef unsigned short u16;
typedef unsigned int u32;
typedef unsigned long long u64;
typedef __attribute__((ext_vector_type(8))) short bf16x8;
typedef __attribute__((ext_vector_type(4))) float f32x4;

constexpr int BB = 2, SS = 2048, HH = 1024, NHEAD = 16, HDIM = 64;

DI u16 f2bf(float f) {
  __hip_bfloat16 h = __float2bfloat16(f);
  union { __hip_bfloat16 h; u16 u; } c; c.h = h; return c.u;
}

// async global->LDS, 16B per lane; LDS dest = wave-uniform base + lane*16
DI void gload_lds16(const void* g, const void* l) {
  __builtin_amdgcn_global_load_lds(
      (const __attribute__((address_space(1))) u32*)(u64)g,
      (__attribute__((address_space(3))) u32*)(u32)(u64)l,
      16, 0, 0);
}

// ---------------------------------------------------------------------------
// x fp32 -> bf16
__global__ void xcast(const float* __restrict__ x, u16* __restrict__ xb) {
  const size_t i = ((size_t)blockIdx.x * 256 + threadIdx.x) * 8;
  float4 f0 = *(const float4*)(x + i);
  float4 f1 = *(const float4*)(x + i + 4);
  bf16x8 v;
  v[0] = (short)f2bf(f0.x); v[1] = (short)f2bf(f0.y);
  v[2] = (short)f2bf(f0.z); v[3] = (short)f2bf(f0.w);
  v[4] = (short)f2bf(f1.x); v[5] = (short)f2bf(f1.y);
  v[6] = (short)f2bf(f1.z); v[7] = (short)f2bf(f1.w);
  *(bf16x8*)(xb + i) = v;
}

// ---------------------------------------------------------------------------
// W fp32 [k][n] -> WT bf16 [n][k], 3 matrices
__global__ void wtrans(const float* __restrict__ Wq, const float* __restrict__ Wk,
                       const float* __restrict__ Wv, u16* __restrict__ WT) {
  __shared__ u16 tile[64][65];
  const float* W = (blockIdx.z == 0) ? Wq : (blockIdx.z == 1) ? Wk : Wv;
  u16* Wt = WT + (size_t)blockIdx.z * HH * HH;
  const int n0 = blockIdx.x * 64, k0 = blockIdx.y * 64;
  for (int i = threadIdx.x; i < 64 * 64; i += 256) {
    int r = i >> 6, c = i & 63;
    tile[r][c] = f2bf(W[(size_t)(k0 + r) * HH + n0 + c]);
  }
  __syncthreads();
  for (int i = threadIdx.x; i < 64 * 64; i += 256) {
    int r = i >> 6, c = i & 63;
    Wt[(size_t)(n0 + r) * HH + k0 + c] = tile[c][r];
  }
}

// ---------------------------------------------------------------------------
// mask int32 {0,1} -> packed bits (bit j of word g = mask[g*64+j])
__global__ void maskpack(const int* __restrict__ mask, u64* __restrict__ mb) {
  const size_t idx = (size_t)blockIdx.x * 256 + threadIdx.x;
  const int v = mask[idx];
  const u64 bal = __ballot(v != 0);
  if ((threadIdx.x & 63) == 0) mb[idx >> 6] = bal;
}

// ---------------------------------------------------------------------------
// C[m][n] = X[m][k] * W[k][n] (+bias) for z in {Q,K,V}; X bf16 [4096][1024],
// WT bf16 [n][k]. Tile 128x128xBK64, 4 waves each 64x64 (4x4 frags 16x16x32).
// LDS rows are 128B; XOR-swizzle byte^=((row&7)<<4) via pre-swizzled global
// source (G21). z==2 (V) writes output TRANSPOSED [bnh][hd][s].
__global__ __launch_bounds__(256) void qkv_gemm(
    const u16* __restrict__ X, const u16* __restrict__ WTall,
    const float* __restrict__ bq, const float* __restrict__ bk,
    const float* __restrict__ bv,
    u16* __restrict__ Qo, u16* __restrict__ Ko, u16* __restrict__ Vo) {
  __shared__ alignas(128) u16 As[128 * 64];
  __shared__ alignas(128) u16 Bs[128 * 64];

  const int z = blockIdx.z;
  const u16* Wt = WTall + (size_t)z * HH * HH;
  const float* bias = (z == 0) ? bq : (z == 1) ? bk : bv;
  u16* Out = (z == 0) ? Qo : (z == 1) ? Ko : Vo;
  // fold 1/sqrt(HD) AND log2(e) into Q (attn works in exp2 domain)
  const float oscale = (z == 0) ? 0.18033688011112042f : 1.0f;

  const int tid = threadIdx.x;
  const int lane = tid & 63;
  const int w = tid >> 6;
  const int wm = (w >> 1) * 64, wn = (w & 1) * 64;
  const int lr = lane & 15, lkg = lane >> 4;
  const int m0 = blockIdx.y * 128, n0 = blockIdx.x * 128;

  u32 srow[4], scol[4];
#pragma unroll
  for (int i = 0; i < 4; ++i) {
    u32 f = i * 4096 + w * 1024 + lane * 16;
    u32 g = f ^ (((f >> 7) & 7) << 4);
    srow[i] = g >> 7;
    scol[i] = (g & 127) >> 1;
  }

  u32 aoff[4][2], boff[4][2];
#pragma unroll
  for (int mf = 0; mf < 4; ++mf)
#pragma unroll
    for (int ks = 0; ks < 2; ++ks) {
      int row = wm + mf * 16 + lr;
      aoff[mf][ks] = (u32)((row * 128 + ks * 64 + lkg * 16) ^ ((row & 7) << 4));
      row = wn + mf * 16 + lr;
      boff[mf][ks] = (u32)((row * 128 + ks * 64 + lkg * 16) ^ ((row & 7) << 4));
    }

  f32x4 acc[4][4];
#pragma unroll
  for (int i = 0; i < 4; ++i)
#pragma unroll
    for (int j = 0; j < 4; ++j) acc[i][j] = {0.f, 0.f, 0.f, 0.f};

  const u16* Xb = X + (size_t)m0 * HH;
  const u16* Wb = Wt + (size_t)n0 * HH;

  auto stage = [&](int kt) {
    const int k0 = kt * 64;
#pragma unroll
    for (int i = 0; i < 4; ++i) {
      gload_lds16(Xb + (size_t)srow[i] * HH + k0 + scol[i],
                  (const char*)As + i * 4096 + w * 1024);
      gload_lds16(Wb + (size_t)srow[i] * HH + k0 + scol[i],
                  (const char*)Bs + i * 4096 + w * 1024);
    }
  };

  stage(0);
  const int NT = HH / 64;  // 16
  for (int kt = 0; kt < NT; ++kt) {
    __syncthreads();
    bf16x8 a[2][4], bfr[2][4];
#pragma unroll
    for (int ks = 0; ks < 2; ++ks)
#pragma unroll
      for (int i = 0; i < 4; ++i) {
        a[ks][i] = *(const bf16x8*)((const char*)As + aoff[i][ks]);
        bfr[ks][i] = *(const bf16x8*)((const char*)Bs + boff[i][ks]);
      }
    __syncthreads();
    if (kt + 1 < NT) stage(kt + 1);
    __builtin_amdgcn_s_setprio(1);
#pragma unroll
    for (int ks = 0; ks < 2; ++ks)
#pragma unroll
      for (int mf = 0; mf < 4; ++mf)
#pragma unroll
        for (int nf = 0; nf < 4; ++nf)
          acc[mf][nf] = __builtin_amdgcn_mfma_f32_16x16x32_bf16(
              a[ks][mf], bfr[ks][nf], acc[mf][nf], 0, 0, 0);
    __builtin_amdgcn_s_setprio(0);
  }

  // epilogue: C/D layout col=lane&15, row=(lane>>4)*4+reg
#pragma unroll
  for (int mf = 0; mf < 4; ++mf)
#pragma unroll
    for (int nf = 0; nf < 4; ++nf) {
      const int gn = n0 + wn + nf * 16 + lr;
      const float bvv = bias[gn];
      const int nh = gn >> 6, hd = gn & 63;
#pragma unroll
      for (int r = 0; r < 4; ++r) {
        const int gm = m0 + wm + mf * 16 + lkg * 4 + r;
        const int bb = gm >> 11, ss = gm & 2047;
        const float v = (acc[mf][nf][r] + bvv) * oscale;
        if (z < 2)
          Out[(((size_t)bb * NHEAD + nh) * SS + ss) * HDIM + hd] = f2bf(v);
        else  // V: fused transpose -> [bnh][hd][s]
          Out[(((size_t)bb * NHEAD + nh) * HDIM + hd) * SS + ss] = f2bf(v);
      }
    }
}

// ---------------------------------------------------------------------------
// Flash attention, swapped-QK^T, no-max softmax (round-4-verified math).
// Block = 4 waves, 64 q-rows (16/wave); KV tiles of 64 in DOUBLE-BUFFERED
// swizzled LDS; ONE barrier per iteration: stage(t+1 -> buf^1) issues right
// after the top barrier and drains at the NEXT top barrier (full-iteration
// latency cover). QK^T = mfma(K,Q) -> S[kv][q]: lane owns q-col=lane&15,
// kv = kvb*16 + lkg*4 + r. Mask: bit-test -> s=-14000 -> exp2 -> 0.
// l via MFMA with all-ones B fragment (lands in oacc row domain).
__global__ __launch_bounds__(256) void attn(
    const u16* __restrict__ Q, const u16* __restrict__ K,
    const u16* __restrict__ Vt, const u64* __restrict__ mb,
    float* __restrict__ out) {
  __shared__ alignas(128) u16 Ks[2][64 * 64];
  __shared__ alignas(128) u16 Vs[2][64 * 64];
  __shared__ alignas(128) u16 Ps[4][16][72];  // per-wave, stride 144B

  const int nh = blockIdx.x, qt = blockIdx.y, b = blockIdx.z;
  const int bnh = b * NHEAD + nh;
  const u16* Qh = Q + (size_t)bnh * SS * HDIM;
  const u16* Kh = K + (size_t)bnh * SS * HDIM;
  const u16* Vh = Vt + (size_t)bnh * HDIM * SS;
  const int q0 = qt * 64;

  const int tid = threadIdx.x, lane = tid & 63, w = tid >> 6;
  const int lr = lane & 15, lkg = lane >> 4;
  const int qrow_lane = q0 + w * 16 + lr;  // this lane's q row (score col)

  // Q fragments (B operand): rows w*16 + lr, k = h*32 + lkg*8 + j
  bf16x8 qf[2];
#pragma unroll
  for (int h = 0; h < 2; ++h)
    qf[h] = *(const bf16x8*)(Qh + (size_t)qrow_lane * HDIM + h * 32 + lkg * 8);

  u32 srow[2], scol[2];
#pragma unroll
  for (int i = 0; i < 2; ++i) {
    u32 f = i * 4096 + w * 1024 + lane * 16;
    u32 g = f ^ (((f >> 7) & 7) << 4);
    srow[i] = g >> 7;
    scol[i] = (g & 127) >> 1;
  }

  auto stage = [&](int t, int buf) {
    const int kv0 = t * 64;
#pragma unroll
    for (int i = 0; i < 2; ++i) {
      gload_lds16(Kh + (size_t)(kv0 + srow[i]) * HDIM + scol[i],
                  (const char*)Ks[buf] + i * 4096 + w * 1024);
      gload_lds16(Vh + (size_t)srow[i] * SS + kv0 + scol[i],
                  (const char*)Vs[buf] + i * 4096 + w * 1024);
    }
  };

  // swizzled read offsets for Ks (row=kv) and Vs (row=hd): same geometry
  u32 koff[4][2];
#pragma unroll
  for (int i = 0; i < 4; ++i)
#pragma unroll
    for (int h = 0; h < 2; ++h) {
      int row = i * 16 + lr;
      koff[i][h] = (u32)((row * 128 + h * 64 + lkg * 16) ^ ((row & 7) << 4));
    }

  // all-ones B fragment for l = P * 1
  bf16x8 ones;
#pragma unroll
  for (int j = 0; j < 8; ++j) ones[j] = (short)0x3F80;

  f32x4 oacc[4];
  f32x4 lacc = {0.f, 0.f, 0.f, 0.f};
#pragma unroll
  for (int n = 0; n < 4; ++n) oacc[n] = {0.f, 0.f, 0.f, 0.f};

  stage(0, 0);
  const int NT = SS / 64;  // 32
  for (int t = 0; t < NT; ++t) {
    const int buf = t & 1;
    // ONE barrier: (a) vmcnt(0) drain => stage(t) complete (issued a full
    // iteration ago); (b) all waves done reading buf^1 => safe to restage it.
    __syncthreads();
    if (t + 1 < NT) stage(t + 1, buf ^ 1);

    const u64 sh =
        mb[((size_t)b * SS + qrow_lane) * (SS / 64) + t] >> (lkg * 4);
    const u32 w01 = (u32)sh, w23 = (u32)(sh >> 32);

    const char* Kbase = (const char*)Ks[buf];
    const char* Vbase = (const char*)Vs[buf];

    // swapped QK^T: sacc[kvb] = S[kv][q], kv rows, q cols
    f32x4 sacc[4];
#pragma unroll
    for (int kvb = 0; kvb < 4; ++kvb) sacc[kvb] = {0.f, 0.f, 0.f, 0.f};
    __builtin_amdgcn_s_setprio(1);
#pragma unroll
    for (int kvb = 0; kvb < 4; ++kvb)
#pragma unroll
      for (int h = 0; h < 2; ++h) {
        const bf16x8 kf = *(const bf16x8*)(Kbase + koff[kvb][h]);
        sacc[kvb] = __builtin_amdgcn_mfma_f32_16x16x32_bf16(
            kf, qf[h], sacc[kvb], 0, 0, 0);
      }
    __builtin_amdgcn_s_setprio(0);

    // no-max softmax: p = exp2(s), masked -> s=-14000 -> 0
#pragma unroll
    for (int kvb = 0; kvb < 4; ++kvb) {
      const u32 word = (kvb < 2) ? w01 : w23;
      const int sb = (kvb & 1) * 16;
      union { u16 h[4]; u64 d; } pk;
#pragma unroll
      for (int r = 0; r < 4; ++r) {
        float s = sacc[kvb][r];
        s = ((word >> (sb + r)) & 1u) ? -14000.0f : s;
        pk.h[r] = f2bf(__builtin_amdgcn_exp2f(s));
      }
      *(u64*)&Ps[w][lr][kvb * 16 + lkg * 4] = pk.d;
    }

    // PV: O[q][hd] += P[q][kv] * V[kv][hd]; l += P * 1
    __builtin_amdgcn_s_setprio(1);
#pragma unroll
    for (int ks = 0; ks < 2; ++ks) {
      const bf16x8 pf = *(const bf16x8*)&Ps[w][lr][ks * 32 + lkg * 8];
#pragma unroll
      for (int n = 0; n < 4; ++n) {
        const bf16x8 vf = *(const bf16x8*)(Vbase + koff[n][ks]);
        oacc[n] = __builtin_amdgcn_mfma_f32_16x16x32_bf16(
            pf, vf, oacc[n], 0, 0, 0);
      }
      lacc = __builtin_amdgcn_mfma_f32_16x16x32_bf16(pf, ones, lacc, 0, 0, 0);
    }
    __builtin_amdgcn_s_setprio(0);
  }

  // epilogue: out[b][q][nh*64+hd] fp32; l already in oacc row domain
#pragma unroll
  for (int r = 0; r < 4; ++r) {
    const float rcp = 1.0f / lacc[r];
    const int qrow = q0 + w * 16 + lkg * 4 + r;
#pragma unroll
    for (int n = 0; n < 4; ++n)
      out[((size_t)b * SS + qrow) * HH + nh * HDIM + n * 16 + lr] =
          oacc[n][r] * rcp;
  }
}

// ---------------------------------------------------------------------------
extern "C" void kernel_launch(void* const* d_in, const int* in_sizes, int n_in,
                              void* d_out, int out_size, void* d_ws,
                              size_t ws_size, hipStream_t stream) {
  const float* x = (const float*)d_in[0];
  const int* mask = (const int*)d_in[1];
  const float* Wq = (const float*)d_in[2];
  const float* bq = (const float*)d_in[3];
  const float* Wk = (const float*)d_in[4];
  const float* bk = (const float*)d_in[5];
  const float* Wv = (const float*)d_in[6];
  const float* bv = (const float*)d_in[7];
  float* out = (float*)d_out;

  char* ws = (char*)d_ws;
  const size_t MB = 1024 * 1024;
  // ws: 25MB used
  u16* Qw = (u16*)(ws + 0 * MB);
  u16* Kw = (u16*)(ws + 8 * MB);
  u16* Vtw = (u16*)(ws + 16 * MB);
  u64* mbp = (u64*)(ws + 24 * MB);
  // d_out doubles as pre-attn scratch (fully dead until attn's epilogue)
  u16* Xb = (u16*)d_out;
  u16* WT = (u16*)((char*)d_out + 8 * MB);

  xcast<<<dim3((BB * SS * HH) / (256 * 8)), 256, 0, stream>>>(x, Xb);
  wtrans<<<dim3(16, 16, 3), 256, 0, stream>>>(Wq, Wk, Wv, WT);
  maskpack<<<dim3((BB * SS * SS) / 256), 256, 0, stream>>>(mask, mbp);
  qkv_gemm<<<dim3(8, 32, 3), 256, 0, stream>>>(Xb, WT, bq, bk, bv, Qw, Kw, Vtw);
  attn<<<dim3(NHEAD, SS / 64, BB), 256, 0, stream>>>(Qw, Kw, Vtw, mbp, out);
}

// Round 8
// 143.072 us; speedup vs baseline: 2.1962x; 1.0499x over previous
//
#include <hip/hip_runtime.h>
#include <hip/hip_bf16.h>
#include <math.h>

// ============================================================================
// MultiHeadAttention: B=2, S=2048, H=1024, NH=16, HD=64
// I/O: fp32 (x, Wq/bq, Wk/bk, Wv/bv), int32 mask; out fp32.
// Internal: bf16 MFMA (16x16x32) with fp32 accum.
// Pipeline: xcast -> wtrans -> maskpack -> qkv_gemm(V fused transpose) -> attn
//
// Round-8 (attn only; round-7 dbuf reverted — it cost occupancy 34->22%, net
// -25%; occupancy > schedule depth here):
//  Base = round-4 verified structure (single K/V buffer, 2 barriers/iter,
//  25.6KB LDS -> 6-block/CU ceiling). Two changes:
//  1) Stage-cover reorder: QK^T reads K from LDS, then V tile -> REGISTERS,
//     then barrier-2, then stage(t+1) into the SAME buffers (ordering vs
//     barriers identical to round-4 => same race-freedom), then softmax+PV
//     from registers. DMA now has the softmax+PV phase (~300-400cyc) of
//     same-wave cover instead of ~0 at the loop-top drain.
//  2) Cheap P pack: round-half-up truncate (bits+0x8000)>>16 instead of
//     software-RNE f2bf (~5-8 ops -> 2 ops per element). p>0 always; masked
//     p remains exact 0 (exp2 underflow). <= 1/2 ulp delta vs RNE.
//
// MEMORY PLAN:
//   d_ws (25MB used):
//     [0,8M)   Qw  bf16 [b][nh][s][hd]  (pre-scaled by 0.125*log2e)
//     [8M,16M) Kw  bf16 [b][nh][s][hd]
//     [16M,24M)Vtw bf16 [b][nh][hd][s]  (transposed, written by qkv_gemm)
//     [24M,25M)mb  u64 bitmask [b][s][S/64]
//   d_out (16MB fp32) doubles as scratch BEFORE attn (dead until epilogue):
//     [0,8M)   Xb  bf16 [b*s][h]
//     [8M,14M) WT  bf16 3x [n][k] (transposed weights)
// ============================================================================

#define DI __device__ __forceinline__

typedef unsigned short u16;
typedef unsigned int u32;
typedef unsigned long long u64;
typedef __attribute__((ext_vector_type(8))) short bf16x8;
typedef __attribute__((ext_vector_type(4))) float f32x4;

constexpr int BB = 2, SS = 2048, HH = 1024, NHEAD = 16, HDIM = 64;

DI u16 f2bf(float f) {
  __hip_bfloat16 h = __float2bfloat16(f);
  union { __hip_bfloat16 h; u16 u; } c; c.h = h; return c.u;
}

// async global->LDS, 16B per lane; LDS dest = wave-uniform base + lane*16
DI void gload_lds16(const void* g, const void* l) {
  __builtin_amdgcn_global_load_lds(
      (const __attribute__((address_space(1))) u32*)(u64)g,
      (__attribute__((address_space(3))) u32*)(u32)(u64)l,
      16, 0, 0);
}

// ---------------------------------------------------------------------------
// x fp32 -> bf16
__global__ void xcast(const float* __restrict__ x, u16* __restrict__ xb) {
  const size_t i = ((size_t)blockIdx.x * 256 + threadIdx.x) * 8;
  float4 f0 = *(const float4*)(x + i);
  float4 f1 = *(const float4*)(x + i + 4);
  bf16x8 v;
  v[0] = (short)f2bf(f0.x); v[1] = (short)f2bf(f0.y);
  v[2] = (short)f2bf(f0.z); v[3] = (short)f2bf(f0.w);
  v[4] = (short)f2bf(f1.x); v[5] = (short)f2bf(f1.y);
  v[6] = (short)f2bf(f1.z); v[7] = (short)f2bf(f1.w);
  *(bf16x8*)(xb + i) = v;
}

// ---------------------------------------------------------------------------
// W fp32 [k][n] -> WT bf16 [n][k], 3 matrices
__global__ void wtrans(const float* __restrict__ Wq, const float* __restrict__ Wk,
                       const float* __restrict__ Wv, u16* __restrict__ WT) {
  __shared__ u16 tile[64][65];
  const float* W = (blockIdx.z == 0) ? Wq : (blockIdx.z == 1) ? Wk : Wv;
  u16* Wt = WT + (size_t)blockIdx.z * HH * HH;
  const int n0 = blockIdx.x * 64, k0 = blockIdx.y * 64;
  for (int i = threadIdx.x; i < 64 * 64; i += 256) {
    int r = i >> 6, c = i & 63;
    tile[r][c] = f2bf(W[(size_t)(k0 + r) * HH + n0 + c]);
  }
  __syncthreads();
  for (int i = threadIdx.x; i < 64 * 64; i += 256) {
    int r = i >> 6, c = i & 63;
    Wt[(size_t)(n0 + r) * HH + k0 + c] = tile[c][r];
  }
}

// ---------------------------------------------------------------------------
// mask int32 {0,1} -> packed bits (bit j of word g = mask[g*64+j])
__global__ void maskpack(const int* __restrict__ mask, u64* __restrict__ mb) {
  const size_t idx = (size_t)blockIdx.x * 256 + threadIdx.x;
  const int v = mask[idx];
  const u64 bal = __ballot(v != 0);
  if ((threadIdx.x & 63) == 0) mb[idx >> 6] = bal;
}

// ---------------------------------------------------------------------------
// C[m][n] = X[m][k] * W[k][n] (+bias) for z in {Q,K,V}; X bf16 [4096][1024],
// WT bf16 [n][k]. Tile 128x128xBK64, 4 waves each 64x64 (4x4 frags 16x16x32).
// LDS rows are 128B; XOR-swizzle byte^=((row&7)<<4) via pre-swizzled global
// source (G21). z==2 (V) writes output TRANSPOSED [bnh][hd][s].
__global__ __launch_bounds__(256) void qkv_gemm(
    const u16* __restrict__ X, const u16* __restrict__ WTall,
    const float* __restrict__ bq, const float* __restrict__ bk,
    const float* __restrict__ bv,
    u16* __restrict__ Qo, u16* __restrict__ Ko, u16* __restrict__ Vo) {
  __shared__ alignas(128) u16 As[128 * 64];
  __shared__ alignas(128) u16 Bs[128 * 64];

  const int z = blockIdx.z;
  const u16* Wt = WTall + (size_t)z * HH * HH;
  const float* bias = (z == 0) ? bq : (z == 1) ? bk : bv;
  u16* Out = (z == 0) ? Qo : (z == 1) ? Ko : Vo;
  // fold 1/sqrt(HD) AND log2(e) into Q (attn works in exp2 domain)
  const float oscale = (z == 0) ? 0.18033688011112042f : 1.0f;

  const int tid = threadIdx.x;
  const int lane = tid & 63;
  const int w = tid >> 6;
  const int wm = (w >> 1) * 64, wn = (w & 1) * 64;
  const int lr = lane & 15, lkg = lane >> 4;
  const int m0 = blockIdx.y * 128, n0 = blockIdx.x * 128;

  u32 srow[4], scol[4];
#pragma unroll
  for (int i = 0; i < 4; ++i) {
    u32 f = i * 4096 + w * 1024 + lane * 16;
    u32 g = f ^ (((f >> 7) & 7) << 4);
    srow[i] = g >> 7;
    scol[i] = (g & 127) >> 1;
  }

  u32 aoff[4][2], boff[4][2];
#pragma unroll
  for (int mf = 0; mf < 4; ++mf)
#pragma unroll
    for (int ks = 0; ks < 2; ++ks) {
      int row = wm + mf * 16 + lr;
      aoff[mf][ks] = (u32)((row * 128 + ks * 64 + lkg * 16) ^ ((row & 7) << 4));
      row = wn + mf * 16 + lr;
      boff[mf][ks] = (u32)((row * 128 + ks * 64 + lkg * 16) ^ ((row & 7) << 4));
    }

  f32x4 acc[4][4];
#pragma unroll
  for (int i = 0; i < 4; ++i)
#pragma unroll
    for (int j = 0; j < 4; ++j) acc[i][j] = {0.f, 0.f, 0.f, 0.f};

  const u16* Xb = X + (size_t)m0 * HH;
  const u16* Wb = Wt + (size_t)n0 * HH;

  auto stage = [&](int kt) {
    const int k0 = kt * 64;
#pragma unroll
    for (int i = 0; i < 4; ++i) {
      gload_lds16(Xb + (size_t)srow[i] * HH + k0 + scol[i],
                  (const char*)As + i * 4096 + w * 1024);
      gload_lds16(Wb + (size_t)srow[i] * HH + k0 + scol[i],
                  (const char*)Bs + i * 4096 + w * 1024);
    }
  };

  stage(0);
  const int NT = HH / 64;  // 16
  for (int kt = 0; kt < NT; ++kt) {
    __syncthreads();
    bf16x8 a[2][4], bfr[2][4];
#pragma unroll
    for (int ks = 0; ks < 2; ++ks)
#pragma unroll
      for (int i = 0; i < 4; ++i) {
        a[ks][i] = *(const bf16x8*)((const char*)As + aoff[i][ks]);
        bfr[ks][i] = *(const bf16x8*)((const char*)Bs + boff[i][ks]);
      }
    __syncthreads();
    if (kt + 1 < NT) stage(kt + 1);
    __builtin_amdgcn_s_setprio(1);
#pragma unroll
    for (int ks = 0; ks < 2; ++ks)
#pragma unroll
      for (int mf = 0; mf < 4; ++mf)
#pragma unroll
        for (int nf = 0; nf < 4; ++nf)
          acc[mf][nf] = __builtin_amdgcn_mfma_f32_16x16x32_bf16(
              a[ks][mf], bfr[ks][nf], acc[mf][nf], 0, 0, 0);
    __builtin_amdgcn_s_setprio(0);
  }

  // epilogue: C/D layout col=lane&15, row=(lane>>4)*4+reg
#pragma unroll
  for (int mf = 0; mf < 4; ++mf)
#pragma unroll
    for (int nf = 0; nf < 4; ++nf) {
      const int gn = n0 + wn + nf * 16 + lr;
      const float bvv = bias[gn];
      const int nh = gn >> 6, hd = gn & 63;
#pragma unroll
      for (int r = 0; r < 4; ++r) {
        const int gm = m0 + wm + mf * 16 + lkg * 4 + r;
        const int bb = gm >> 11, ss = gm & 2047;
        const float v = (acc[mf][nf][r] + bvv) * oscale;
        if (z < 2)
          Out[(((size_t)bb * NHEAD + nh) * SS + ss) * HDIM + hd] = f2bf(v);
        else  // V: fused transpose -> [bnh][hd][s]
          Out[(((size_t)bb * NHEAD + nh) * HDIM + hd) * SS + ss] = f2bf(v);
      }
    }
}

// ---------------------------------------------------------------------------
// Flash attention, swapped-QK^T, no-max softmax (round-4-verified math).
// Block = 4 waves, 64 q-rows (16/wave); KV tiles of 64 in single-buffered
// swizzled LDS (25.6KB). Iteration: barrier -> QK^T (K from LDS) -> V tile
// to REGS -> barrier -> stage(t+1) -> softmax -> PV (regs). Stage DMA gets
// the softmax+PV phase of cover; drains at next loop-top barrier.
// QK^T = mfma(K,Q) -> S[kv][q]: lane owns q-col=lane&15, kv=kvb*16+lkg*4+r.
// Mask: bit-test -> s=-14000 -> exp2 -> 0. P pack: (bits+0x8000)>>16.
// l via MFMA with all-ones B fragment (lands in oacc row domain).
__global__ __launch_bounds__(256) void attn(
    const u16* __restrict__ Q, const u16* __restrict__ K,
    const u16* __restrict__ Vt, const u64* __restrict__ mb,
    float* __restrict__ out) {
  __shared__ alignas(128) u16 Ks[64 * 64];
  __shared__ alignas(128) u16 Vs[64 * 64];
  __shared__ alignas(128) u16 Ps[4][16][72];  // per-wave, stride 144B

  const int nh = blockIdx.x, qt = blockIdx.y, b = blockIdx.z;
  const int bnh = b * NHEAD + nh;
  const u16* Qh = Q + (size_t)bnh * SS * HDIM;
  const u16* Kh = K + (size_t)bnh * SS * HDIM;
  const u16* Vh = Vt + (size_t)bnh * HDIM * SS;
  const int q0 = qt * 64;

  const int tid = threadIdx.x, lane = tid & 63, w = tid >> 6;
  const int lr = lane & 15, lkg = lane >> 4;
  const int qrow_lane = q0 + w * 16 + lr;  // this lane's q row (score col)

  // Q fragments (B operand): rows w*16 + lr, k = h*32 + lkg*8 + j
  bf16x8 qf[2];
#pragma unroll
  for (int h = 0; h < 2; ++h)
    qf[h] = *(const bf16x8*)(Qh + (size_t)qrow_lane * HDIM + h * 32 + lkg * 8);

  u32 srow[2], scol[2];
#pragma unroll
  for (int i = 0; i < 2; ++i) {
    u32 f = i * 4096 + w * 1024 + lane * 16;
    u32 g = f ^ (((f >> 7) & 7) << 4);
    srow[i] = g >> 7;
    scol[i] = (g & 127) >> 1;
  }

  auto stage = [&](int t) {
    const int kv0 = t * 64;
#pragma unroll
    for (int i = 0; i < 2; ++i) {
      gload_lds16(Kh + (size_t)(kv0 + srow[i]) * HDIM + scol[i],
                  (const char*)Ks + i * 4096 + w * 1024);
      gload_lds16(Vh + (size_t)srow[i] * SS + kv0 + scol[i],
                  (const char*)Vs + i * 4096 + w * 1024);
    }
  };

  // swizzled read offsets for Ks (row=kv) and Vs (row=hd): same geometry
  u32 koff[4][2];
#pragma unroll
  for (int i = 0; i < 4; ++i)
#pragma unroll
    for (int h = 0; h < 2; ++h) {
      int row = i * 16 + lr;
      koff[i][h] = (u32)((row * 128 + h * 64 + lkg * 16) ^ ((row & 7) << 4));
    }

  // all-ones B fragment for l = P * 1
  bf16x8 ones;
#pragma unroll
  for (int j = 0; j < 8; ++j) ones[j] = (short)0x3F80;

  f32x4 oacc[4];
  f32x4 lacc = {0.f, 0.f, 0.f, 0.f};
#pragma unroll
  for (int n = 0; n < 4; ++n) oacc[n] = {0.f, 0.f, 0.f, 0.f};

  stage(0);
  const int NT = SS / 64;  // 32
  for (int t = 0; t < NT; ++t) {
    __syncthreads();  // stage(t) complete (barrier drains vmcnt)

    const u64 sh =
        mb[((size_t)b * SS + qrow_lane) * (SS / 64) + t] >> (lkg * 4);
    const u32 w01 = (u32)sh, w23 = (u32)(sh >> 32);

    // swapped QK^T: sacc[kvb] = S[kv][q]; K fragments straight from LDS
    f32x4 sacc[4];
#pragma unroll
    for (int kvb = 0; kvb < 4; ++kvb) sacc[kvb] = {0.f, 0.f, 0.f, 0.f};
    __builtin_amdgcn_s_setprio(1);
#pragma unroll
    for (int kvb = 0; kvb < 4; ++kvb)
#pragma unroll
      for (int h = 0; h < 2; ++h) {
        const bf16x8 kf = *(const bf16x8*)((const char*)Ks + koff[kvb][h]);
        sacc[kvb] = __builtin_amdgcn_mfma_f32_16x16x32_bf16(
            kf, qf[h], sacc[kvb], 0, 0, 0);
      }
    __builtin_amdgcn_s_setprio(0);

    // V tile -> registers (so LDS can be restaged under softmax+PV)
    bf16x8 vf[4][2];
#pragma unroll
    for (int n = 0; n < 4; ++n)
#pragma unroll
      for (int ks = 0; ks < 2; ++ks)
        vf[n][ks] = *(const bf16x8*)((const char*)Vs + koff[n][ks]);

    __syncthreads();  // all waves done reading Ks/Vs
    if (t + 1 < NT) stage(t + 1);  // lands under softmax+PV; drains next top

    // no-max softmax: p = exp2(s), masked -> s=-14000 -> 0.
    // pack: round-half-up truncate (bits+0x8000)>>16  (p > 0 always)
#pragma unroll
    for (int kvb = 0; kvb < 4; ++kvb) {
      const u32 word = (kvb < 2) ? w01 : w23;
      const int sb = (kvb & 1) * 16;
      union { u16 h[4]; u64 d; } pk;
#pragma unroll
      for (int r = 0; r < 4; ++r) {
        float s = sacc[kvb][r];
        s = ((word >> (sb + r)) & 1u) ? -14000.0f : s;
        const float p = __builtin_amdgcn_exp2f(s);
        pk.h[r] = (u16)((__builtin_bit_cast(u32, p) + 0x8000u) >> 16);
      }
      *(u64*)&Ps[w][lr][kvb * 16 + lkg * 4] = pk.d;
    }

    // PV: O[q][hd] += P[q][kv] * V[kv][hd]; l += P * 1
    __builtin_amdgcn_s_setprio(1);
#pragma unroll
    for (int ks = 0; ks < 2; ++ks) {
      const bf16x8 pf = *(const bf16x8*)&Ps[w][lr][ks * 32 + lkg * 8];
#pragma unroll
      for (int n = 0; n < 4; ++n)
        oacc[n] = __builtin_amdgcn_mfma_f32_16x16x32_bf16(
            pf, vf[n][ks], oacc[n], 0, 0, 0);
      lacc = __builtin_amdgcn_mfma_f32_16x16x32_bf16(pf, ones, lacc, 0, 0, 0);
    }
    __builtin_amdgcn_s_setprio(0);
  }

  // epilogue: out[b][q][nh*64+hd] fp32; l already in oacc row domain
#pragma unroll
  for (int r = 0; r < 4; ++r) {
    const float rcp = 1.0f / lacc[r];
    const int qrow = q0 + w * 16 + lkg * 4 + r;
#pragma unroll
    for (int n = 0; n < 4; ++n)
      out[((size_t)b * SS + qrow) * HH + nh * HDIM + n * 16 + lr] =
          oacc[n][r] * rcp;
  }
}

// ---------------------------------------------------------------------------
extern "C" void kernel_launch(void* const* d_in, const int* in_sizes, int n_in,
                              void* d_out, int out_size, void* d_ws,
                              size_t ws_size, hipStream_t stream) {
  const float* x = (const float*)d_in[0];
  const int* mask = (const int*)d_in[1];
  const float* Wq = (const float*)d_in[2];
  const float* bq = (const float*)d_in[3];
  const float* Wk = (const float*)d_in[4];
  const float* bk = (const float*)d_in[5];
  const float* Wv = (const float*)d_in[6];
  const float* bv = (const float*)d_in[7];
  float* out = (float*)d_out;

  char* ws = (char*)d_ws;
  const size_t MB = 1024 * 1024;
  // ws: 25MB used
  u16* Qw = (u16*)(ws + 0 * MB);
  u16* Kw = (u16*)(ws + 8 * MB);
  u16* Vtw = (u16*)(ws + 16 * MB);
  u64* mbp = (u64*)(ws + 24 * MB);
  // d_out doubles as pre-attn scratch (fully dead until attn's epilogue)
  u16* Xb = (u16*)d_out;
  u16* WT = (u16*)((char*)d_out + 8 * MB);

  xcast<<<dim3((BB * SS * HH) / (256 * 8)), 256, 0, stream>>>(x, Xb);
  wtrans<<<dim3(16, 16, 3), 256, 0, stream>>>(Wq, Wk, Wv, WT);
  maskpack<<<dim3((BB * SS * SS) / 256), 256, 0, stream>>>(mask, mbp);
  qkv_gemm<<<dim3(8, 32, 3), 256, 0, stream>>>(Xb, WT, bq, bk, bv, Qw, Kw, Vtw);
  attn<<<dim3(NHEAD, SS / 64, BB), 256, 0, stream>>>(Qw, Kw, Vtw, mbp, out);
}

// Round 9
// 136.995 us; speedup vs baseline: 2.2936x; 1.0444x over previous
//
#include <hip/hip_runtime.h>
#include <hip/hip_bf16.h>
#include <math.h>

// ============================================================================
// MultiHeadAttention: B=2, S=2048, H=1024, NH=16, HD=64
// I/O: fp32 (x, Wq/bq, Wk/bk, Wv/bv), int32 mask; out fp32.
// Internal: bf16 MFMA (16x16x32) with fp32 accum.
// Pipeline: xcast -> wtrans -> maskpack -> qkv_gemm(V fused transpose) -> attn
//
// Round-9: bisect round-8. The stage reorder is reverted (it split the
// barrier regions -> 82us regression; round-4's sync shape is a local
// optimum: dbuf=89us, direct-VGPR=254us, reorder=82us all lost to it).
// SINGLE lever kept: cheap P pack (bits+0x8000)>>16 instead of software-RNE
// f2bf in attn's softmax (~5-7 ops -> 2 ops per element; VALU is the
// critical resource at VALUBusy 51%). Attn otherwise byte-identical to the
// verified 71.5us round-4 kernel.
//
// MEMORY PLAN:
//   d_ws (25MB used):
//     [0,8M)   Qw  bf16 [b][nh][s][hd]  (pre-scaled by 0.125*log2e)
//     [8M,16M) Kw  bf16 [b][nh][s][hd]
//     [16M,24M)Vtw bf16 [b][nh][hd][s]  (transposed, written by qkv_gemm)
//     [24M,25M)mb  u64 bitmask [b][s][S/64]
//   d_out (16MB fp32) doubles as scratch BEFORE attn (dead until epilogue):
//     [0,8M)   Xb  bf16 [b*s][h]
//     [8M,14M) WT  bf16 3x [n][k] (transposed weights)
// ============================================================================

#define DI __device__ __forceinline__

typedef unsigned short u16;
typedef unsigned int u32;
typedef unsigned long long u64;
typedef __attribute__((ext_vector_type(8))) short bf16x8;
typedef __attribute__((ext_vector_type(4))) float f32x4;

constexpr int BB = 2, SS = 2048, HH = 1024, NHEAD = 16, HDIM = 64;

DI u16 f2bf(float f) {
  __hip_bfloat16 h = __float2bfloat16(f);
  union { __hip_bfloat16 h; u16 u; } c; c.h = h; return c.u;
}

// async global->LDS, 16B per lane; LDS dest = wave-uniform base + lane*16
DI void gload_lds16(const void* g, const void* l) {
  __builtin_amdgcn_global_load_lds(
      (const __attribute__((address_space(1))) u32*)(u64)g,
      (__attribute__((address_space(3))) u32*)(u32)(u64)l,
      16, 0, 0);
}

// ---------------------------------------------------------------------------
// x fp32 -> bf16
__global__ void xcast(const float* __restrict__ x, u16* __restrict__ xb) {
  const size_t i = ((size_t)blockIdx.x * 256 + threadIdx.x) * 8;
  float4 f0 = *(const float4*)(x + i);
  float4 f1 = *(const float4*)(x + i + 4);
  bf16x8 v;
  v[0] = (short)f2bf(f0.x); v[1] = (short)f2bf(f0.y);
  v[2] = (short)f2bf(f0.z); v[3] = (short)f2bf(f0.w);
  v[4] = (short)f2bf(f1.x); v[5] = (short)f2bf(f1.y);
  v[6] = (short)f2bf(f1.z); v[7] = (short)f2bf(f1.w);
  *(bf16x8*)(xb + i) = v;
}

// ---------------------------------------------------------------------------
// W fp32 [k][n] -> WT bf16 [n][k], 3 matrices
__global__ void wtrans(const float* __restrict__ Wq, const float* __restrict__ Wk,
                       const float* __restrict__ Wv, u16* __restrict__ WT) {
  __shared__ u16 tile[64][65];
  const float* W = (blockIdx.z == 0) ? Wq : (blockIdx.z == 1) ? Wk : Wv;
  u16* Wt = WT + (size_t)blockIdx.z * HH * HH;
  const int n0 = blockIdx.x * 64, k0 = blockIdx.y * 64;
  for (int i = threadIdx.x; i < 64 * 64; i += 256) {
    int r = i >> 6, c = i & 63;
    tile[r][c] = f2bf(W[(size_t)(k0 + r) * HH + n0 + c]);
  }
  __syncthreads();
  for (int i = threadIdx.x; i < 64 * 64; i += 256) {
    int r = i >> 6, c = i & 63;
    Wt[(size_t)(n0 + r) * HH + k0 + c] = tile[c][r];
  }
}

// ---------------------------------------------------------------------------
// mask int32 {0,1} -> packed bits (bit j of word g = mask[g*64+j])
__global__ void maskpack(const int* __restrict__ mask, u64* __restrict__ mb) {
  const size_t idx = (size_t)blockIdx.x * 256 + threadIdx.x;
  const int v = mask[idx];
  const u64 bal = __ballot(v != 0);
  if ((threadIdx.x & 63) == 0) mb[idx >> 6] = bal;
}

// ---------------------------------------------------------------------------
// C[m][n] = X[m][k] * W[k][n] (+bias) for z in {Q,K,V}; X bf16 [4096][1024],
// WT bf16 [n][k]. Tile 128x128xBK64, 4 waves each 64x64 (4x4 frags 16x16x32).
// LDS rows are 128B; XOR-swizzle byte^=((row&7)<<4) via pre-swizzled global
// source (G21). z==2 (V) writes output TRANSPOSED [bnh][hd][s].
__global__ __launch_bounds__(256) void qkv_gemm(
    const u16* __restrict__ X, const u16* __restrict__ WTall,
    const float* __restrict__ bq, const float* __restrict__ bk,
    const float* __restrict__ bv,
    u16* __restrict__ Qo, u16* __restrict__ Ko, u16* __restrict__ Vo) {
  __shared__ alignas(128) u16 As[128 * 64];
  __shared__ alignas(128) u16 Bs[128 * 64];

  const int z = blockIdx.z;
  const u16* Wt = WTall + (size_t)z * HH * HH;
  const float* bias = (z == 0) ? bq : (z == 1) ? bk : bv;
  u16* Out = (z == 0) ? Qo : (z == 1) ? Ko : Vo;
  // fold 1/sqrt(HD) AND log2(e) into Q (attn works in exp2 domain)
  const float oscale = (z == 0) ? 0.18033688011112042f : 1.0f;

  const int tid = threadIdx.x;
  const int lane = tid & 63;
  const int w = tid >> 6;
  const int wm = (w >> 1) * 64, wn = (w & 1) * 64;
  const int lr = lane & 15, lkg = lane >> 4;
  const int m0 = blockIdx.y * 128, n0 = blockIdx.x * 128;

  u32 srow[4], scol[4];
#pragma unroll
  for (int i = 0; i < 4; ++i) {
    u32 f = i * 4096 + w * 1024 + lane * 16;
    u32 g = f ^ (((f >> 7) & 7) << 4);
    srow[i] = g >> 7;
    scol[i] = (g & 127) >> 1;
  }

  u32 aoff[4][2], boff[4][2];
#pragma unroll
  for (int mf = 0; mf < 4; ++mf)
#pragma unroll
    for (int ks = 0; ks < 2; ++ks) {
      int row = wm + mf * 16 + lr;
      aoff[mf][ks] = (u32)((row * 128 + ks * 64 + lkg * 16) ^ ((row & 7) << 4));
      row = wn + mf * 16 + lr;
      boff[mf][ks] = (u32)((row * 128 + ks * 64 + lkg * 16) ^ ((row & 7) << 4));
    }

  f32x4 acc[4][4];
#pragma unroll
  for (int i = 0; i < 4; ++i)
#pragma unroll
    for (int j = 0; j < 4; ++j) acc[i][j] = {0.f, 0.f, 0.f, 0.f};

  const u16* Xb = X + (size_t)m0 * HH;
  const u16* Wb = Wt + (size_t)n0 * HH;

  auto stage = [&](int kt) {
    const int k0 = kt * 64;
#pragma unroll
    for (int i = 0; i < 4; ++i) {
      gload_lds16(Xb + (size_t)srow[i] * HH + k0 + scol[i],
                  (const char*)As + i * 4096 + w * 1024);
      gload_lds16(Wb + (size_t)srow[i] * HH + k0 + scol[i],
                  (const char*)Bs + i * 4096 + w * 1024);
    }
  };

  stage(0);
  const int NT = HH / 64;  // 16
  for (int kt = 0; kt < NT; ++kt) {
    __syncthreads();
    bf16x8 a[2][4], bfr[2][4];
#pragma unroll
    for (int ks = 0; ks < 2; ++ks)
#pragma unroll
      for (int i = 0; i < 4; ++i) {
        a[ks][i] = *(const bf16x8*)((const char*)As + aoff[i][ks]);
        bfr[ks][i] = *(const bf16x8*)((const char*)Bs + boff[i][ks]);
      }
    __syncthreads();
    if (kt + 1 < NT) stage(kt + 1);
    __builtin_amdgcn_s_setprio(1);
#pragma unroll
    for (int ks = 0; ks < 2; ++ks)
#pragma unroll
      for (int mf = 0; mf < 4; ++mf)
#pragma unroll
        for (int nf = 0; nf < 4; ++nf)
          acc[mf][nf] = __builtin_amdgcn_mfma_f32_16x16x32_bf16(
              a[ks][mf], bfr[ks][nf], acc[mf][nf], 0, 0, 0);
    __builtin_amdgcn_s_setprio(0);
  }

  // epilogue: C/D layout col=lane&15, row=(lane>>4)*4+reg
#pragma unroll
  for (int mf = 0; mf < 4; ++mf)
#pragma unroll
    for (int nf = 0; nf < 4; ++nf) {
      const int gn = n0 + wn + nf * 16 + lr;
      const float bvv = bias[gn];
      const int nh = gn >> 6, hd = gn & 63;
#pragma unroll
      for (int r = 0; r < 4; ++r) {
        const int gm = m0 + wm + mf * 16 + lkg * 4 + r;
        const int bb = gm >> 11, ss = gm & 2047;
        const float v = (acc[mf][nf][r] + bvv) * oscale;
        if (z < 2)
          Out[(((size_t)bb * NHEAD + nh) * SS + ss) * HDIM + hd] = f2bf(v);
        else  // V: fused transpose -> [bnh][hd][s]
          Out[(((size_t)bb * NHEAD + nh) * HDIM + hd) * SS + ss] = f2bf(v);
      }
    }
}

// ---------------------------------------------------------------------------
// Flash attention, swapped-QK^T, no-max softmax. Round-4 verified structure:
// block = 4 waves, 64 q-rows (16/wave); KV tiles of 64 in single-buffered
// swizzled LDS; barrier -> QK^T -> softmax -> PV (V from LDS) -> barrier ->
// stage(t+1). QK^T = mfma(K,Q) -> S[kv][q]: lane owns q-col=lane&15,
// kv = kvb*16 + lkg*4 + r. Mask: bit-test -> s=-14000 -> exp2 -> 0.
// P pack: round-half-up truncate (bits+0x8000)>>16 (the ONE change vs r4).
// l via MFMA with all-ones B fragment (lands in oacc row domain).
__global__ __launch_bounds__(256) void attn(
    const u16* __restrict__ Q, const u16* __restrict__ K,
    const u16* __restrict__ Vt, const u64* __restrict__ mb,
    float* __restrict__ out) {
  __shared__ alignas(128) u16 Ks[64 * 64];
  __shared__ alignas(128) u16 Vs[64 * 64];
  __shared__ alignas(128) u16 Ps[4][16][72];  // per-wave, stride 144B

  const int nh = blockIdx.x, qt = blockIdx.y, b = blockIdx.z;
  const int bnh = b * NHEAD + nh;
  const u16* Qh = Q + (size_t)bnh * SS * HDIM;
  const u16* Kh = K + (size_t)bnh * SS * HDIM;
  const u16* Vh = Vt + (size_t)bnh * HDIM * SS;
  const int q0 = qt * 64;

  const int tid = threadIdx.x, lane = tid & 63, w = tid >> 6;
  const int lr = lane & 15, lkg = lane >> 4;
  const int qrow_lane = q0 + w * 16 + lr;  // this lane's q row (score col)

  // Q fragments (B operand): rows w*16 + lr, k = h*32 + lkg*8 + j
  bf16x8 qf[2];
#pragma unroll
  for (int h = 0; h < 2; ++h)
    qf[h] = *(const bf16x8*)(Qh + (size_t)qrow_lane * HDIM + h * 32 + lkg * 8);

  u32 srow[2], scol[2];
#pragma unroll
  for (int i = 0; i < 2; ++i) {
    u32 f = i * 4096 + w * 1024 + lane * 16;
    u32 g = f ^ (((f >> 7) & 7) << 4);
    srow[i] = g >> 7;
    scol[i] = (g & 127) >> 1;
  }

  auto stage = [&](int t) {
    const int kv0 = t * 64;
#pragma unroll
    for (int i = 0; i < 2; ++i) {
      gload_lds16(Kh + (size_t)(kv0 + srow[i]) * HDIM + scol[i],
                  (const char*)Ks + i * 4096 + w * 1024);
      gload_lds16(Vh + (size_t)srow[i] * SS + kv0 + scol[i],
                  (const char*)Vs + i * 4096 + w * 1024);
    }
  };

  // swizzled read offsets for Ks (row=kv) and Vs (row=hd): same geometry
  u32 koff[4][2];
#pragma unroll
  for (int i = 0; i < 4; ++i)
#pragma unroll
    for (int h = 0; h < 2; ++h) {
      int row = i * 16 + lr;
      koff[i][h] = (u32)((row * 128 + h * 64 + lkg * 16) ^ ((row & 7) << 4));
    }

  // all-ones B fragment for l = P * 1
  bf16x8 ones;
#pragma unroll
  for (int j = 0; j < 8; ++j) ones[j] = (short)0x3F80;

  f32x4 oacc[4];
  f32x4 lacc = {0.f, 0.f, 0.f, 0.f};
#pragma unroll
  for (int n = 0; n < 4; ++n) oacc[n] = {0.f, 0.f, 0.f, 0.f};

  stage(0);
  const int NT = SS / 64;  // 32
  for (int t = 0; t < NT; ++t) {
    __syncthreads();  // K/V tile ready (stage(t) drained here)

    // mask word for this lane's q row; pre-shift so bit (kvb*16+r) applies
    const u64 sh =
        mb[((size_t)b * SS + qrow_lane) * (SS / 64) + t] >> (lkg * 4);
    const u32 w01 = (u32)sh, w23 = (u32)(sh >> 32);

    // swapped QK^T: sacc[kvb] = S[kv][q], kv rows, q cols
    f32x4 sacc[4];
#pragma unroll
    for (int kvb = 0; kvb < 4; ++kvb) sacc[kvb] = {0.f, 0.f, 0.f, 0.f};
    __builtin_amdgcn_s_setprio(1);
#pragma unroll
    for (int kvb = 0; kvb < 4; ++kvb)
#pragma unroll
      for (int h = 0; h < 2; ++h) {
        const bf16x8 kf = *(const bf16x8*)((const char*)Ks + koff[kvb][h]);
        sacc[kvb] = __builtin_amdgcn_mfma_f32_16x16x32_bf16(
            kf, qf[h], sacc[kvb], 0, 0, 0);
      }
    __builtin_amdgcn_s_setprio(0);

    // no-max softmax: p = exp2(s), masked -> s=-14000 -> 0.
    // pack: round-half-up truncate (bits+0x8000)>>16 (p>0 always; masked
    // p is exact 0 so truncate keeps it 0)
#pragma unroll
    for (int kvb = 0; kvb < 4; ++kvb) {
      const u32 word = (kvb < 2) ? w01 : w23;
      const int sb = (kvb & 1) * 16;
      union { u16 h[4]; u64 d; } pk;
#pragma unroll
      for (int r = 0; r < 4; ++r) {
        float s = sacc[kvb][r];
        s = ((word >> (sb + r)) & 1u) ? -14000.0f : s;
        const float p = __builtin_amdgcn_exp2f(s);
        pk.h[r] = (u16)((__builtin_bit_cast(u32, p) + 0x8000u) >> 16);
      }
      *(u64*)&Ps[w][lr][kvb * 16 + lkg * 4] = pk.d;
    }

    // PV: O[q][hd] += P[q][kv] * V[kv][hd]; l += P * 1
    __builtin_amdgcn_s_setprio(1);
#pragma unroll
    for (int ks = 0; ks < 2; ++ks) {
      const bf16x8 pf = *(const bf16x8*)&Ps[w][lr][ks * 32 + lkg * 8];
#pragma unroll
      for (int n = 0; n < 4; ++n) {
        const bf16x8 vf = *(const bf16x8*)((const char*)Vs + koff[n][ks]);
        oacc[n] = __builtin_amdgcn_mfma_f32_16x16x32_bf16(
            pf, vf, oacc[n], 0, 0, 0);
      }
      lacc = __builtin_amdgcn_mfma_f32_16x16x32_bf16(pf, ones, lacc, 0, 0, 0);
    }
    __builtin_amdgcn_s_setprio(0);

    __syncthreads();  // all waves done with Ks/Vs
    if (t + 1 < NT) stage(t + 1);
  }

  // epilogue: out[b][q][nh*64+hd] fp32; l already in oacc row domain
#pragma unroll
  for (int r = 0; r < 4; ++r) {
    const float rcp = 1.0f / lacc[r];
    const int qrow = q0 + w * 16 + lkg * 4 + r;
#pragma unroll
    for (int n = 0; n < 4; ++n)
      out[((size_t)b * SS + qrow) * HH + nh * HDIM + n * 16 + lr] =
          oacc[n][r] * rcp;
  }
}

// ---------------------------------------------------------------------------
extern "C" void kernel_launch(void* const* d_in, const int* in_sizes, int n_in,
                              void* d_out, int out_size, void* d_ws,
                              size_t ws_size, hipStream_t stream) {
  const float* x = (const float*)d_in[0];
  const int* mask = (const int*)d_in[1];
  const float* Wq = (const float*)d_in[2];
  const float* bq = (const float*)d_in[3];
  const float* Wk = (const float*)d_in[4];
  const float* bk = (const float*)d_in[5];
  const float* Wv = (const float*)d_in[6];
  const float* bv = (const float*)d_in[7];
  float* out = (float*)d_out;

  char* ws = (char*)d_ws;
  const size_t MB = 1024 * 1024;
  // ws: 25MB used
  u16* Qw = (u16*)(ws + 0 * MB);
  u16* Kw = (u16*)(ws + 8 * MB);
  u16* Vtw = (u16*)(ws + 16 * MB);
  u64* mbp = (u64*)(ws + 24 * MB);
  // d_out doubles as pre-attn scratch (fully dead until attn's epilogue)
  u16* Xb = (u16*)d_out;
  u16* WT = (u16*)((char*)d_out + 8 * MB);

  xcast<<<dim3((BB * SS * HH) / (256 * 8)), 256, 0, stream>>>(x, Xb);
  wtrans<<<dim3(16, 16, 3), 256, 0, stream>>>(Wq, Wk, Wv, WT);
  maskpack<<<dim3((BB * SS * SS) / 256), 256, 0, stream>>>(mask, mbp);
  qkv_gemm<<<dim3(8, 32, 3), 256, 0, stream>>>(Xb, WT, bq, bk, bv, Qw, Kw, Vtw);
  attn<<<dim3(NHEAD, SS / 64, BB), 256, 0, stream>>>(Qw, Kw, Vtw, mbp, out);
}

// Round 10
// 131.994 us; speedup vs baseline: 2.3805x; 1.0379x over previous
//
#include <hip/hip_runtime.h>
#include <hip/hip_bf16.h>
#include <math.h>

// ============================================================================
// MultiHeadAttention: B=2, S=2048, H=1024, NH=16, HD=64
// I/O: fp32 (x, Wq/bq, Wk/bk, Wv/bv), int32 mask; out fp32.
// Internal: bf16 MFMA (16x16x32) with fp32 accum.
// Pipeline: xcast -> wtrans -> maskpack -> qkv_gemm(V fused transpose) -> attn
//
// Round-10 (attn): base = round-4 verified structure + f2bf pack (71.5us;
// round-9 proved the "cheap pack" was a 4us regression - f2bf is ~1 HW op).
// ONE new lever: in-block kv-split. 512-thread block = 2 wave-groups of 4;
// group g handles kv half [g*1024,(g+1)*1024) of the SAME 64 q-rows with its
// own K/V LDS tiles (identical r4 inner loop, 16 tiles each). No-max softmax
// => partials combine by ADDITION: group1 dumps (O,l) to LDS, group0 adds,
// normalizes, writes. Occupancy cap 50% -> 75% (24 waves/CU), half the
// serial length per wave.
//
// MEMORY PLAN:
//   d_ws (25MB used):
//     [0,8M)   Qw  bf16 [b][nh][s][hd]  (pre-scaled by 0.125*log2e)
//     [8M,16M) Kw  bf16 [b][nh][s][hd]
//     [16M,24M)Vtw bf16 [b][nh][hd][s]  (transposed, written by qkv_gemm)
//     [24M,25M)mb  u64 bitmask [b][s][S/64]
//   d_out (16MB fp32) doubles as scratch BEFORE attn (dead until epilogue):
//     [0,8M)   Xb  bf16 [b*s][h]
//     [8M,14M) WT  bf16 3x [n][k] (transposed weights)
// ============================================================================

#define DI __device__ __forceinline__

typedef unsigned short u16;
typedef unsigned int u32;
typedef unsigned long long u64;
typedef __attribute__((ext_vector_type(8))) short bf16x8;
typedef __attribute__((ext_vector_type(4))) float f32x4;

constexpr int BB = 2, SS = 2048, HH = 1024, NHEAD = 16, HDIM = 64;

DI u16 f2bf(float f) {
  __hip_bfloat16 h = __float2bfloat16(f);
  union { __hip_bfloat16 h; u16 u; } c; c.h = h; return c.u;
}

// async global->LDS, 16B per lane; LDS dest = wave-uniform base + lane*16
DI void gload_lds16(const void* g, const void* l) {
  __builtin_amdgcn_global_load_lds(
      (const __attribute__((address_space(1))) u32*)(u64)g,
      (__attribute__((address_space(3))) u32*)(u32)(u64)l,
      16, 0, 0);
}

// ---------------------------------------------------------------------------
// x fp32 -> bf16
__global__ void xcast(const float* __restrict__ x, u16* __restrict__ xb) {
  const size_t i = ((size_t)blockIdx.x * 256 + threadIdx.x) * 8;
  float4 f0 = *(const float4*)(x + i);
  float4 f1 = *(const float4*)(x + i + 4);
  bf16x8 v;
  v[0] = (short)f2bf(f0.x); v[1] = (short)f2bf(f0.y);
  v[2] = (short)f2bf(f0.z); v[3] = (short)f2bf(f0.w);
  v[4] = (short)f2bf(f1.x); v[5] = (short)f2bf(f1.y);
  v[6] = (short)f2bf(f1.z); v[7] = (short)f2bf(f1.w);
  *(bf16x8*)(xb + i) = v;
}

// ---------------------------------------------------------------------------
// W fp32 [k][n] -> WT bf16 [n][k], 3 matrices
__global__ void wtrans(const float* __restrict__ Wq, const float* __restrict__ Wk,
                       const float* __restrict__ Wv, u16* __restrict__ WT) {
  __shared__ u16 tile[64][65];
  const float* W = (blockIdx.z == 0) ? Wq : (blockIdx.z == 1) ? Wk : Wv;
  u16* Wt = WT + (size_t)blockIdx.z * HH * HH;
  const int n0 = blockIdx.x * 64, k0 = blockIdx.y * 64;
  for (int i = threadIdx.x; i < 64 * 64; i += 256) {
    int r = i >> 6, c = i & 63;
    tile[r][c] = f2bf(W[(size_t)(k0 + r) * HH + n0 + c]);
  }
  __syncthreads();
  for (int i = threadIdx.x; i < 64 * 64; i += 256) {
    int r = i >> 6, c = i & 63;
    Wt[(size_t)(n0 + r) * HH + k0 + c] = tile[c][r];
  }
}

// ---------------------------------------------------------------------------
// mask int32 {0,1} -> packed bits (bit j of word g = mask[g*64+j])
__global__ void maskpack(const int* __restrict__ mask, u64* __restrict__ mb) {
  const size_t idx = (size_t)blockIdx.x * 256 + threadIdx.x;
  const int v = mask[idx];
  const u64 bal = __ballot(v != 0);
  if ((threadIdx.x & 63) == 0) mb[idx >> 6] = bal;
}

// ---------------------------------------------------------------------------
// C[m][n] = X[m][k] * W[k][n] (+bias) for z in {Q,K,V}; X bf16 [4096][1024],
// WT bf16 [n][k]. Tile 128x128xBK64, 4 waves each 64x64 (4x4 frags 16x16x32).
// LDS rows are 128B; XOR-swizzle byte^=((row&7)<<4) via pre-swizzled global
// source (G21). z==2 (V) writes output TRANSPOSED [bnh][hd][s].
__global__ __launch_bounds__(256) void qkv_gemm(
    const u16* __restrict__ X, const u16* __restrict__ WTall,
    const float* __restrict__ bq, const float* __restrict__ bk,
    const float* __restrict__ bv,
    u16* __restrict__ Qo, u16* __restrict__ Ko, u16* __restrict__ Vo) {
  __shared__ alignas(128) u16 As[128 * 64];
  __shared__ alignas(128) u16 Bs[128 * 64];

  const int z = blockIdx.z;
  const u16* Wt = WTall + (size_t)z * HH * HH;
  const float* bias = (z == 0) ? bq : (z == 1) ? bk : bv;
  u16* Out = (z == 0) ? Qo : (z == 1) ? Ko : Vo;
  // fold 1/sqrt(HD) AND log2(e) into Q (attn works in exp2 domain)
  const float oscale = (z == 0) ? 0.18033688011112042f : 1.0f;

  const int tid = threadIdx.x;
  const int lane = tid & 63;
  const int w = tid >> 6;
  const int wm = (w >> 1) * 64, wn = (w & 1) * 64;
  const int lr = lane & 15, lkg = lane >> 4;
  const int m0 = blockIdx.y * 128, n0 = blockIdx.x * 128;

  u32 srow[4], scol[4];
#pragma unroll
  for (int i = 0; i < 4; ++i) {
    u32 f = i * 4096 + w * 1024 + lane * 16;
    u32 g = f ^ (((f >> 7) & 7) << 4);
    srow[i] = g >> 7;
    scol[i] = (g & 127) >> 1;
  }

  u32 aoff[4][2], boff[4][2];
#pragma unroll
  for (int mf = 0; mf < 4; ++mf)
#pragma unroll
    for (int ks = 0; ks < 2; ++ks) {
      int row = wm + mf * 16 + lr;
      aoff[mf][ks] = (u32)((row * 128 + ks * 64 + lkg * 16) ^ ((row & 7) << 4));
      row = wn + mf * 16 + lr;
      boff[mf][ks] = (u32)((row * 128 + ks * 64 + lkg * 16) ^ ((row & 7) << 4));
    }

  f32x4 acc[4][4];
#pragma unroll
  for (int i = 0; i < 4; ++i)
#pragma unroll
    for (int j = 0; j < 4; ++j) acc[i][j] = {0.f, 0.f, 0.f, 0.f};

  const u16* Xb = X + (size_t)m0 * HH;
  const u16* Wb = Wt + (size_t)n0 * HH;

  auto stage = [&](int kt) {
    const int k0 = kt * 64;
#pragma unroll
    for (int i = 0; i < 4; ++i) {
      gload_lds16(Xb + (size_t)srow[i] * HH + k0 + scol[i],
                  (const char*)As + i * 4096 + w * 1024);
      gload_lds16(Wb + (size_t)srow[i] * HH + k0 + scol[i],
                  (const char*)Bs + i * 4096 + w * 1024);
    }
  };

  stage(0);
  const int NT = HH / 64;  // 16
  for (int kt = 0; kt < NT; ++kt) {
    __syncthreads();
    bf16x8 a[2][4], bfr[2][4];
#pragma unroll
    for (int ks = 0; ks < 2; ++ks)
#pragma unroll
      for (int i = 0; i < 4; ++i) {
        a[ks][i] = *(const bf16x8*)((const char*)As + aoff[i][ks]);
        bfr[ks][i] = *(const bf16x8*)((const char*)Bs + boff[i][ks]);
      }
    __syncthreads();
    if (kt + 1 < NT) stage(kt + 1);
    __builtin_amdgcn_s_setprio(1);
#pragma unroll
    for (int ks = 0; ks < 2; ++ks)
#pragma unroll
      for (int mf = 0; mf < 4; ++mf)
#pragma unroll
        for (int nf = 0; nf < 4; ++nf)
          acc[mf][nf] = __builtin_amdgcn_mfma_f32_16x16x32_bf16(
              a[ks][mf], bfr[ks][nf], acc[mf][nf], 0, 0, 0);
    __builtin_amdgcn_s_setprio(0);
  }

  // epilogue: C/D layout col=lane&15, row=(lane>>4)*4+reg
#pragma unroll
  for (int mf = 0; mf < 4; ++mf)
#pragma unroll
    for (int nf = 0; nf < 4; ++nf) {
      const int gn = n0 + wn + nf * 16 + lr;
      const float bvv = bias[gn];
      const int nh = gn >> 6, hd = gn & 63;
#pragma unroll
      for (int r = 0; r < 4; ++r) {
        const int gm = m0 + wm + mf * 16 + lkg * 4 + r;
        const int bb = gm >> 11, ss = gm & 2047;
        const float v = (acc[mf][nf][r] + bvv) * oscale;
        if (z < 2)
          Out[(((size_t)bb * NHEAD + nh) * SS + ss) * HDIM + hd] = f2bf(v);
        else  // V: fused transpose -> [bnh][hd][s]
          Out[(((size_t)bb * NHEAD + nh) * HDIM + hd) * SS + ss] = f2bf(v);
      }
    }
}

// ---------------------------------------------------------------------------
// Flash attention, swapped-QK^T, no-max softmax, IN-BLOCK KV-SPLIT.
// 512 threads = 8 waves = 2 groups of 4. Group g processes kv half
// [g*1024,(g+1)*1024) of the same 64 q-rows (16/wave), staging its own K/V
// tiles; inner loop is the round-4 verified shape (barrier -> QK^T ->
// softmax(f2bf) -> PV -> barrier -> stage(t+1)), 16 tiles per group.
// No-max softmax => partial (O,l) combine by addition: group1 -> LDS (SoA,
// conflict-free), group0 adds + normalizes + writes.
__global__ __launch_bounds__(512) void attn(
    const u16* __restrict__ Q, const u16* __restrict__ K,
    const u16* __restrict__ Vt, const u64* __restrict__ mb,
    float* __restrict__ out) {
  // manual layout: Ks[2][4096] u16 | Vs[2][4096] u16 | Ps[8][16][72] u16
  // combine buffer (20KB float) aliases the Ks/Vs region after the loop.
  __shared__ alignas(128) char smem[16384 + 16384 + 8 * 16 * 72 * 2];
  u16* Ks = (u16*)smem;                       // [2][64*64]
  u16* Vs = (u16*)(smem + 16384);             // [2][64*64]
  typedef u16 PsRow[16][72];
  PsRow* Ps = (PsRow*)(smem + 32768);         // [8][16][72]
  float* cmb = (float*)smem;                  // 20 * 256 floats = 20KB

  const int nh = blockIdx.x, qt = blockIdx.y, b = blockIdx.z;
  const int bnh = b * NHEAD + nh;
  const u16* Qh = Q + (size_t)bnh * SS * HDIM;
  const u16* Kh = K + (size_t)bnh * SS * HDIM;
  const u16* Vh = Vt + (size_t)bnh * HDIM * SS;
  const int q0 = qt * 64;

  const int tid = threadIdx.x, lane = tid & 63, w = tid >> 6;  // w in [0,8)
  const int g = w >> 2, wg = w & 3;           // group, wave-within-group
  const int lr = lane & 15, lkg = lane >> 4;
  const int qrow_lane = q0 + wg * 16 + lr;    // this lane's q row (score col)
  const int kvbase = g * (SS / 2);            // group's kv origin

  // Q fragments (B operand): rows wg*16 + lr, k = h*32 + lkg*8 + j
  bf16x8 qf[2];
#pragma unroll
  for (int h = 0; h < 2; ++h)
    qf[h] = *(const bf16x8*)(Qh + (size_t)qrow_lane * HDIM + h * 32 + lkg * 8);

  u32 srow[2], scol[2];
#pragma unroll
  for (int i = 0; i < 2; ++i) {
    u32 f = i * 4096 + wg * 1024 + lane * 16;
    u32 gg = f ^ (((f >> 7) & 7) << 4);
    srow[i] = gg >> 7;
    scol[i] = (gg & 127) >> 1;
  }

  auto stage = [&](int t) {
    const int kv0 = kvbase + t * 64;
#pragma unroll
    for (int i = 0; i < 2; ++i) {
      gload_lds16(Kh + (size_t)(kv0 + srow[i]) * HDIM + scol[i],
                  (const char*)(Ks + g * 4096) + i * 4096 + wg * 1024);
      gload_lds16(Vh + (size_t)srow[i] * SS + kv0 + scol[i],
                  (const char*)(Vs + g * 4096) + i * 4096 + wg * 1024);
    }
  };

  // swizzled read offsets for Ks (row=kv) and Vs (row=hd): same geometry
  u32 koff[4][2];
#pragma unroll
  for (int i = 0; i < 4; ++i)
#pragma unroll
    for (int h = 0; h < 2; ++h) {
      int row = i * 16 + lr;
      koff[i][h] = (u32)((row * 128 + h * 64 + lkg * 16) ^ ((row & 7) << 4));
    }

  // all-ones B fragment for l = P * 1
  bf16x8 ones;
#pragma unroll
  for (int j = 0; j < 8; ++j) ones[j] = (short)0x3F80;

  f32x4 oacc[4];
  f32x4 lacc = {0.f, 0.f, 0.f, 0.f};
#pragma unroll
  for (int n = 0; n < 4; ++n) oacc[n] = {0.f, 0.f, 0.f, 0.f};

  stage(0);
  const int NT = SS / 128;  // 16 tiles per group
  const char* Kbase = (const char*)(Ks + g * 4096);
  const char* Vbase = (const char*)(Vs + g * 4096);
  for (int t = 0; t < NT; ++t) {
    __syncthreads();  // both groups' stage(t) drained

    // mask word for this lane's q row (tile index = g*16 + t)
    const u64 sh =
        mb[((size_t)b * SS + qrow_lane) * (SS / 64) + g * NT + t] >> (lkg * 4);
    const u32 w01 = (u32)sh, w23 = (u32)(sh >> 32);

    // swapped QK^T: sacc[kvb] = S[kv][q], kv rows, q cols
    f32x4 sacc[4];
#pragma unroll
    for (int kvb = 0; kvb < 4; ++kvb) sacc[kvb] = {0.f, 0.f, 0.f, 0.f};
    __builtin_amdgcn_s_setprio(1);
#pragma unroll
    for (int kvb = 0; kvb < 4; ++kvb)
#pragma unroll
      for (int h = 0; h < 2; ++h) {
        const bf16x8 kf = *(const bf16x8*)(Kbase + koff[kvb][h]);
        sacc[kvb] = __builtin_amdgcn_mfma_f32_16x16x32_bf16(
            kf, qf[h], sacc[kvb], 0, 0, 0);
      }
    __builtin_amdgcn_s_setprio(0);

    // no-max softmax: p = exp2(s), masked -> s=-14000 -> exp2 -> 0 (f2bf pack)
#pragma unroll
    for (int kvb = 0; kvb < 4; ++kvb) {
      const u32 word = (kvb < 2) ? w01 : w23;
      const int sb = (kvb & 1) * 16;
      union { u16 h[4]; u64 d; } pk;
#pragma unroll
      for (int r = 0; r < 4; ++r) {
        float s = sacc[kvb][r];
        s = ((word >> (sb + r)) & 1u) ? -14000.0f : s;
        pk.h[r] = f2bf(__builtin_amdgcn_exp2f(s));
      }
      *(u64*)&Ps[w][lr][kvb * 16 + lkg * 4] = pk.d;
    }

    // PV: O[q][hd] += P[q][kv] * V[kv][hd]; l += P * 1
    __builtin_amdgcn_s_setprio(1);
#pragma unroll
    for (int ks = 0; ks < 2; ++ks) {
      const bf16x8 pf = *(const bf16x8*)&Ps[w][lr][ks * 32 + lkg * 8];
#pragma unroll
      for (int n = 0; n < 4; ++n) {
        const bf16x8 vf = *(const bf16x8*)(Vbase + koff[n][ks]);
        oacc[n] = __builtin_amdgcn_mfma_f32_16x16x32_bf16(
            pf, vf, oacc[n], 0, 0, 0);
      }
      lacc = __builtin_amdgcn_mfma_f32_16x16x32_bf16(pf, ones, lacc, 0, 0, 0);
    }
    __builtin_amdgcn_s_setprio(0);

    __syncthreads();  // all waves done with Ks/Vs
    if (t + 1 < NT) stage(t + 1);
  }

  // combine: group1 dumps (O,l) to LDS (SoA: word j*256+lid, conflict-free);
  // group0 adds, normalizes, writes. Aliases Ks/Vs (dead after final barrier).
  const int lid = wg * 64 + lane;  // [0,256) within group
  if (g == 1) {
#pragma unroll
    for (int n = 0; n < 4; ++n)
#pragma unroll
      for (int r = 0; r < 4; ++r) cmb[(n * 4 + r) * 256 + lid] = oacc[n][r];
#pragma unroll
    for (int r = 0; r < 4; ++r) cmb[(16 + r) * 256 + lid] = lacc[r];
  }
  __syncthreads();
  if (g == 0) {
#pragma unroll
    for (int r = 0; r < 4; ++r) {
      const float l = lacc[r] + cmb[(16 + r) * 256 + lid];
      const float rcp = 1.0f / l;
      const int qrow = q0 + wg * 16 + lkg * 4 + r;
#pragma unroll
      for (int n = 0; n < 4; ++n) {
        const float o = oacc[n][r] + cmb[(n * 4 + r) * 256 + lid];
        out[((size_t)b * SS + qrow) * HH + nh * HDIM + n * 16 + lr] = o * rcp;
      }
    }
  }
}

// ---------------------------------------------------------------------------
extern "C" void kernel_launch(void* const* d_in, const int* in_sizes, int n_in,
                              void* d_out, int out_size, void* d_ws,
                              size_t ws_size, hipStream_t stream) {
  const float* x = (const float*)d_in[0];
  const int* mask = (const int*)d_in[1];
  const float* Wq = (const float*)d_in[2];
  const float* bq = (const float*)d_in[3];
  const float* Wk = (const float*)d_in[4];
  const float* bk = (const float*)d_in[5];
  const float* Wv = (const float*)d_in[6];
  const float* bv = (const float*)d_in[7];
  float* out = (float*)d_out;

  char* ws = (char*)d_ws;
  const size_t MB = 1024 * 1024;
  // ws: 25MB used
  u16* Qw = (u16*)(ws + 0 * MB);
  u16* Kw = (u16*)(ws + 8 * MB);
  u16* Vtw = (u16*)(ws + 16 * MB);
  u64* mbp = (u64*)(ws + 24 * MB);
  // d_out doubles as pre-attn scratch (fully dead until attn's epilogue)
  u16* Xb = (u16*)d_out;
  u16* WT = (u16*)((char*)d_out + 8 * MB);

  xcast<<<dim3((BB * SS * HH) / (256 * 8)), 256, 0, stream>>>(x, Xb);
  wtrans<<<dim3(16, 16, 3), 256, 0, stream>>>(Wq, Wk, Wv, WT);
  maskpack<<<dim3((BB * SS * SS) / 256), 256, 0, stream>>>(mask, mbp);
  qkv_gemm<<<dim3(8, 32, 3), 256, 0, stream>>>(Xb, WT, bq, bk, bv, Qw, Kw, Vtw);
  attn<<<dim3(NHEAD, SS / 64, BB), 512, 0, stream>>>(Qw, Kw, Vtw, mbp, out);
}